// Round 7
// baseline (46.051 us; speedup 1.0000x reference)
//
#include <hip/hip_runtime.h>
#include <hip/hip_bf16.h>

#define SCALE (1.0f/16.0f)

typedef __attribute__((ext_vector_type(8))) short short8;
typedef __attribute__((ext_vector_type(4))) short short4v;
typedef __attribute__((ext_vector_type(2))) float f32x2;
typedef __attribute__((ext_vector_type(4))) float f32x4;
typedef __attribute__((ext_vector_type(16))) float f32x16;
typedef unsigned int u32;

__device__ __forceinline__ f32x2 unpk(u32 u) {
    f32x2 r;
    r[0] = __uint_as_float(u << 16);
    r[1] = __uint_as_float(u & 0xffff0000u);
    return r;
}
__device__ __forceinline__ u32 pk2bf(f32x2 v) {
    __hip_bfloat16 h0 = __float2bfloat16(v[0]);
    __hip_bfloat16 h1 = __float2bfloat16(v[1]);
    return (u32)*(unsigned short*)&h0 | ((u32)*(unsigned short*)&h1 << 16);
}

// ---------------- K1: transpose features f32 [256][4096] -> bf16 [4096][256] ----------------
__global__ void k_transpose(const float* __restrict__ feat, __hip_bfloat16* __restrict__ featT) {
    __shared__ float t[64][65];
    int cb = (blockIdx.x >> 6) << 6;
    int pb = (blockIdx.x & 63) << 6;
    int lx = threadIdx.x & 63, ly = threadIdx.x >> 6;
#pragma unroll
    for (int i = 0; i < 16; ++i) {
        int cl = i*4 + ly;
        t[cl][lx] = feat[(size_t)(cb + cl) * 4096 + pb + lx];
    }
    __syncthreads();
#pragma unroll
    for (int i = 0; i < 16; ++i) {
        int pl = i*4 + ly;
        featT[(size_t)(pb + pl) * 256 + cb + lx] = __float2bfloat16(t[lx][pl]);
    }
}

// ---------------- K2: permute W -> 32x32x16 MFMA A-fragment order ----------------
// chunk ch = ((j*8 + ot)*16 + sk)*64 + l : 8 bf16 of W[o = ot*32 + (l&31)][k = j*256 + sk*16 + (l>>5)*8 + i]
__global__ void k_permw(const float* __restrict__ wf, __hip_bfloat16* __restrict__ wr) {
    int ch = blockIdx.x * 256 + threadIdx.x;   // 65536 chunks
    int l  = ch & 63;
    int sk = (ch >> 6) & 15;
    int ot = (ch >> 10) & 7;
    int j  = ch >> 13;
    int o = ot*32 + (l & 31);
    int k = j*256 + sk*16 + (l >> 5)*8;
    const float* src = wf + (size_t)o*2048 + k;
    f32x4 a = *(const f32x4*)src;
    f32x4 b = *(const f32x4*)(src + 4);
    short8 p;
#pragma unroll
    for (int u = 0; u < 4; ++u) {
        __hip_bfloat16 h = __float2bfloat16(a[u]); p[u] = *(short*)&h;
    }
#pragma unroll
    for (int u = 0; u < 4; ++u) {
        __hip_bfloat16 h = __float2bfloat16(b[u]); p[4+u] = *(short*)&h;
    }
    *((short8*)wr + ch) = p;
}

// ---------------- K3: fused ROIAlign + GEMM, split-K across blocks ----------------
// Grid 512: bid -> (n, jq). Block = 512 thr = 8 waves, each wave one 32-o tile.
// Per block: pool 2 context boxes (j = jq*2, jq*2+1) into Pl[0/1], GEMM both K-slices,
// write f32 partials part[jq][n][256][49]. Only 2 barriers. XCD-grouped: jq-partners same XCD.
__global__ void __launch_bounds__(512, 4) k_fused(
    const __hip_bfloat16* __restrict__ featT,
    const float* __restrict__ boxes,
    const __hip_bfloat16* __restrict__ wr,
    float* __restrict__ part)
{
    __shared__ char Pl[2][32768];          // [jj][64 hw][256 c] bf16, XOR-swizzled rows
    __shared__ f32x4 tabs[2][2][7];        // [jj][isy][h] = {pos0(abs), a0, a1, a2}

    int tid = threadIdx.x;
    int lane = tid & 63, wid = tid >> 6;
    int bid = blockIdx.x;
    int n  = (bid & 7) + ((bid >> 5) << 3);   // partners (n, jq 0..3) share bid%8 -> same XCD
    int jq = (bid >> 3) & 3;

    int nb_base = (n & 15) * 8;
    int off = n >> 4;
    int t3 = off + (off >= 4 ? 1 : 0);
    int ci = t3 / 3, cj = t3 - ci*3;

    // ---- phase T: 3-tap separable tables for both boxes (waves 4..7) ----
    if (wid >= 4) {
        int s = wid - 4;
        int jj = s >> 1, isy = s & 1;
        int nbx = nb_base + jq*2 + jj;
        float bx1 = boxes[nbx*4+0], by1 = boxes[nbx*4+1];
        float bx2 = boxes[nbx*4+2], by2 = boxes[nbx*4+3];
        float w3 = (bx2-bx1)*(1.f/3.f), h3 = (by2-by1)*(1.f/3.f);
        float org  = isy ? (by1 + ci*h3)*SCALE - 0.5f : (bx1 + cj*w3)*SCALE - 0.5f;
        float step = (isy ? h3 : w3) * (SCALE*(1.f/14.f));   // half-bin
        float sc = isy ? 0.25f : 1.f;
        float p = org + ((float)lane + 0.5f)*step;
        float pc = fminf(fmaxf(p, 0.f), 63.f);
        float fl = fminf(floorf(pc), 62.f);
        float fr = pc - fl;
        float c0 = __shfl(fl, 2*lane);
        float c1 = __shfl(fl, 2*lane+1);
        float f  = __shfl(fr, 2*lane);
        float f2 = __shfl(fr, 2*lane+1);
        float d = c1 - c0;                 // 0 or 1
        float a0 = sc*((1.f-f) + (1.f-d)*(1.f-f2));
        float a1 = sc*(f + (1.f-d)*f2 + d*(1.f-f2));
        float a2 = sc*(d*f2);
        if (lane < 7) {
            f32x4 e; e[0] = c0; e[1] = a0; e[2] = a1; e[3] = a2;
            tabs[jj][isy][lane] = e;
        }
    }
    __syncthreads();

    // ---- phase P: pool both boxes (9-tap separable, direct from featT) ----
    int cp = tid & 127, e0 = tid >> 7;     // e0 0..3
    const u32* fp32 = (const u32*)featT;   // pair view: pixel*128 + cp
#pragma unroll
    for (int jj = 0; jj < 2; ++jj) {
        for (int e = e0; e < 49; e += 4) {
            int h = (e*37) >> 8;           // e/7
            int w = e - h*7;
            f32x4 tx = tabs[jj][0][w], ty = tabs[jj][1][h];
            int x0 = (int)tx[0], y0 = (int)ty[0];
            int x2 = min(x0 + 2, 63), y2 = min(y0 + 2, 63);
            int r0 = (y0*64 + x0)*128 + cp;
            int r1 = r0 + 8192;
            int r2 = (y2*64 + x0)*128 + cp;
            int dx2 = (x2 - x0)*128;
            u32 F00 = fp32[r0], F01 = fp32[r0+128], F02 = fp32[r0+dx2];
            u32 F10 = fp32[r1], F11 = fp32[r1+128], F12 = fp32[r1+dx2];
            u32 F20 = fp32[r2], F21 = fp32[r2+128], F22 = fp32[r2+dx2];
            f32x2 row0 = tx[1]*unpk(F00) + tx[2]*unpk(F01) + tx[3]*unpk(F02);
            f32x2 row1 = tx[1]*unpk(F10) + tx[2]*unpk(F11) + tx[3]*unpk(F12);
            f32x2 row2 = tx[1]*unpk(F20) + tx[2]*unpk(F21) + tx[3]*unpk(F22);
            f32x2 v = ty[1]*row0 + ty[2]*row1 + ty[3]*row2;   // 0.25 folded into ty
            *(u32*)(Pl[jj] + e*512 + ((cp*4) ^ ((e & 7) << 4))) = pk2bf(v);
        }
    }
    __syncthreads();

    // ---- phase G: GEMM both K-slices, accumulate ----
    int ot = wid;                 // 8 o-tiles of 32
    int r31 = lane & 31;
    f32x16 acc[2];
#pragma unroll
    for (int hwt = 0; hwt < 2; ++hwt)
#pragma unroll
        for (int i = 0; i < 16; ++i) acc[hwt][i] = 0.f;

#pragma unroll
    for (int jj = 0; jj < 2; ++jj) {
        int j = jq*2 + jj;
        const short8* wb = (const short8*)wr + ((size_t)((j*8 + ot)*16))*64 + lane;
#pragma unroll
        for (int sb = 0; sb < 4; ++sb) {
            short8 wf4[4];
#pragma unroll
            for (int s4 = 0; s4 < 4; ++s4) wf4[s4] = wb[(sb*4 + s4)*64];
#pragma unroll
            for (int s4 = 0; s4 < 4; ++s4) {
                int sk = sb*4 + s4;
#pragma unroll
                for (int hwt = 0; hwt < 2; ++hwt) {
                    int byo = (hwt*32 + r31)*512 + ((sk*32 + (lane>>5)*16) ^ ((r31 & 7) << 4));
                    short8 pf = *(const short8*)(Pl[jj] + byo);
                    acc[hwt] = __builtin_amdgcn_mfma_f32_32x32x16_bf16(wf4[s4], pf, acc[hwt], 0, 0, 0);
                }
            }
        }
    }

    // ---- store partials: part[jq][n][o][hw] ----
    float* pb = part + ((size_t)(jq*128 + n)) * 12544;
#pragma unroll
    for (int hwt = 0; hwt < 2; ++hwt) {
        int hw = hwt*32 + r31;
        if (hw < 49) {
#pragma unroll
            for (int reg = 0; reg < 16; ++reg) {
                int o = ot*32 + (reg & 3) + 8*(reg >> 2) + 4*(lane >> 5);
                pb[o*49 + hw] = acc[hwt][reg];
            }
        }
    }
}

// ---------------- K4: reduce 4 partials + bias + relu ----------------
// Block rb: n = (rb&7) + 8*((rb>>3)&15), og = rb>>7 (16 o's per block). XCD-matched to producers.
__global__ void __launch_bounds__(256) k_reduce(const float* __restrict__ part,
                                                const float* __restrict__ bfuse,
                                                float* __restrict__ out) {
    int rb = blockIdx.x;              // 0..2047
    int x = rb & 7, h = rb >> 3;      // h 0..255
    int n = x + ((h & 15) << 3);
    int og = h >> 4;                  // 0..15
    const size_t S = 1605632;         // 128*256*49
    size_t base = (size_t)n*12544 + og*16*49;
    for (int i = threadIdx.x; i < 784; i += 256) {
        int o_l = (i * 1338) >> 16;   // i/49 for i<=783
        int hw = i - o_l*49;
        int o = og*16 + o_l;
        size_t e = base + o_l*49 + hw;
        float s = part[e] + part[e+S] + part[e+2*S] + part[e+3*S] + bfuse[o];
        out[(size_t)n*12544 + o*49 + hw] = fmaxf(s, 0.f);
    }
}

extern "C" void kernel_launch(void* const* d_in, const int* in_sizes, int n_in,
                              void* d_out, int out_size, void* d_ws, size_t ws_size,
                              hipStream_t stream) {
    const float* feat  = (const float*)d_in[0];   // [256,64,64]
    const float* boxes = (const float*)d_in[1];   // [128,4]
    const float* wf    = (const float*)d_in[2];   // [256,2048]
    const float* bfuse = (const float*)d_in[3];   // [256]
    float* out = (float*)d_out;                   // [128,256,7,7]

    char* ws = (char*)d_ws;
    __hip_bfloat16* wr    = (__hip_bfloat16*)ws;                 // 1 MB (permuted W)
    __hip_bfloat16* featT = (__hip_bfloat16*)(ws + (1u<<20));    // 2 MB
    float* part           = (float*)(ws + (4u<<20));             // 24.5 MB (4 K-slices)

    k_transpose<<<256, 256, 0, stream>>>(feat, featT);
    k_permw<<<256, 256, 0, stream>>>(wf, wr);
    k_fused<<<512, 512, 0, stream>>>(featT, boxes, wr, part);
    k_reduce<<<2048, 256, 0, stream>>>(part, bfuse, out);
}